// Round 16
// baseline (36.506 us; speedup 1.0000x reference)
//
#include <hip/hip_runtime.h>

#define HW 4096

typedef float f32x4 __attribute__((ext_vector_type(4)));
typedef __bf16 bf16x8 __attribute__((ext_vector_type(8)));
typedef unsigned short u16x8 __attribute__((ext_vector_type(8)));

union F8 { bf16x8 v; unsigned long long q[2]; unsigned short u[8]; __bf16 h[8]; };

__device__ inline unsigned short f2bf(float f) {
    unsigned int u = __builtin_bit_cast(unsigned int, f);
    u += 0x7fffu + ((u >> 16) & 1u);   // RNE
    return (unsigned short)(u >> 16);
}
__device__ inline float bf2f(unsigned short h) {
    unsigned int u = ((unsigned int)h) << 16;
    return __builtin_bit_cast(float, u);
}
__device__ inline bf16x8 frag_lo(const unsigned short* p) {
    F8 f; f.q[0] = *(const unsigned long long*)p; f.q[1] = 0ull; return f.v;
}

#define MFMA16(a,b,c) __builtin_amdgcn_mfma_f32_16x16x32_bf16(a, b, c, 0, 0, 0)
#define EXP2(x) __builtin_amdgcn_exp2f(x)

// ---------------------------------------------------------------------------
// Kernel 1: projections — unchanged (r12 form).
// ---------------------------------------------------------------------------
__global__ __launch_bounds__(256, 4) void proj_kernel(
    const float* __restrict__ x,
    const float* __restrict__ Wq, const float* __restrict__ bq,
    const float* __restrict__ Wk, const float* __restrict__ bk,
    const float* __restrict__ Wv, const float* __restrict__ bv,
    unsigned short* __restrict__ qpack, unsigned short* __restrict__ kpack,
    unsigned short* __restrict__ vt3)
{
    const float A2 = 0.51006977f;      // log2(e)/sqrt(8), folded into q
    __shared__ float ldsW[80][64];
    __shared__ float ldsB[80];

    const int blk   = blockIdx.x;
    const int b     = blk >> 8;
    const int rest  = blk & 255;
    const int ntile = rest >> 2;
    const int rg    = rest & 3;
    const int tid   = threadIdx.x;
    const int w     = tid >> 6;
    const int lane  = tid & 63;
    const int n     = ntile * 64 + lane;

#pragma unroll
    for (int kk = 0; kk < 5; ++kk) {
        const int idx = tid + kk * 256;
        const int r   = idx >> 4;
        const int c   = (idx & 15) << 2;
        f32x4 val;
        if (r < 8) { val = *(const f32x4*)(Wq + r * 64 + c); val *= A2; }
        else if (r < 16) val = *(const f32x4*)(Wk + (r - 8) * 64 + c);
        else             val = *(const f32x4*)(Wv + (r - 16) * 64 + c);
        *(f32x4*)(&ldsW[r][c]) = val;
    }
    if (tid < 80) {
        float bb = (tid < 8) ? bq[tid] * A2
                 : (tid < 16) ? bk[tid - 8] : bv[tid - 16];
        ldsB[tid] = bb;
    }
    __syncthreads();

    const float* xb = x + (size_t)b * 64 * HW + n;
    float xv[64];
#pragma unroll
    for (int c = 0; c < 64; ++c) xv[c] = xb[c * HW];

    auto rowdot = [&](int row) -> float {
        const float* wr = &ldsW[row][0];
        float a0 = 0.f, a1 = 0.f, a2 = 0.f, a3 = 0.f;
#pragma unroll
        for (int c4 = 0; c4 < 16; ++c4) {
            f32x4 wv = *(const f32x4*)(wr + c4 * 4);
            a0 = fmaf(wv[0], xv[c4*4+0], a0);
            a1 = fmaf(wv[1], xv[c4*4+1], a1);
            a2 = fmaf(wv[2], xv[c4*4+2], a2);
            a3 = fmaf(wv[3], xv[c4*4+3], a3);
        }
        return (a0 + a1) + (a2 + a3) + ldsB[row];
    };

    const int vslot = (((n >> 2) & 3) << 3) + (n & 3) + (((n >> 4) & 1) << 2);
    unsigned short* vB = vt3 + ((size_t)(b * 128 + (n >> 5)) * 64) * 32 + vslot;

    const int r0 = rg * 20 + w * 5;
#pragma unroll
    for (int rr = 0; rr < 5; ++rr) {
        const int row = r0 + rr;
        float val = rowdot(row);
        if (row < 8) {
            qpack[(size_t)(b * HW + n) * 8 + row] = f2bf(val);
        } else if (row < 16) {
            kpack[(size_t)(b * HW + n) * 8 + (row - 8)] = f2bf(val);
        } else {
            vB[(size_t)(row - 16) * 32] = f2bf(val);
        }
    }
}

// ---------------------------------------------------------------------------
// Kernel 2: attention + skip, v11 = v8's work at 2x the occupancy.
// r14/r15 nulls: neither less VALU (v8) nor prefetch (v9) moved A=24us ->
// the stall is intra-wave dependency gaps at only 4 waves/SIMD (~55% issue
// efficiency per r13 cycle accounting). VGPR=64 allows 32 waves/CU (2048/64);
// the old grid (2 blocks/CU x 8 waves) capped at 16. v11: 16-wave blocks
// (1024 thr), wave = 32q x 64c x 256m (8 chunks); grid 512 unchanged ->
// 2 blocks/CU x 16 waves = 32 waves/CU = 100% cap. Chip-wide V/K/exp2/MFMA
// work identical to v8. (1024,2) -> VGPR cap 64 (= v8's compiled count;
// watch WRITE_SIZE for spill).
// ---------------------------------------------------------------------------
__global__ __launch_bounds__(1024, 2) void attn_kernel(
    const unsigned short* __restrict__ qpack,
    const unsigned short* __restrict__ kpack,
    const unsigned short* __restrict__ vt3,
    const float* __restrict__ x,
    const float* __restrict__ gamma,
    float* __restrict__ out)
{
    const int blk  = blockIdx.x;
    const int slot = blk & 7;              // XCD slot = (b<<1)|(qt&1)
    const int j8   = blk >> 3;             // 0..63
    const int b    = slot >> 1;
    const int qt   = (j8 << 1) | (slot & 1);   // 0..127
    const int nb   = qt * 32;
    const int tid  = threadIdx.x;
    const int w    = tid >> 6;             // 0..15 = m-slice
    const int lane = tid & 63;
    const int g    = lane >> 4;
    const int ln   = lane & 15;

    __shared__ unsigned short ldsO[16][32][66];  // bf16 partials, padded
    __shared__ float ldsL[16][32];

    F8 zf; zf.q[0] = 0ull; zf.q[1] = 0ull;       // zero fragment (g>=1 pads)

    // Q B-frags for 2 query subtiles: only g=0 lanes carry data
    bf16x8 qf[2];
#pragma unroll
    for (int i = 0; i < 2; ++i)
        qf[i] = (g == 0)
              ? frag_lo(qpack + (size_t)(b * HW + nb + 16 * i + ln) * 8)
              : zf.v;

    F8 onesu;
#pragma unroll
    for (int e = 0; e < 8; ++e) onesu.u[e] = 0x3F80;   // bf16 1.0
    const bf16x8 ones = onesu.v;

    f32x4 o[2][4], ol[2];
#pragma unroll
    for (int i = 0; i < 2; ++i) {
#pragma unroll
        for (int j = 0; j < 4; ++j) o[i][j] = (f32x4){0,0,0,0};
        ol[i] = (f32x4){0,0,0,0};
    }

    const int mq = w * 256;                // this wave's m-slice (256 m)
    const unsigned short* kb = kpack + (size_t)(b * HW + mq + ln) * 8;
    const unsigned short* vwin = vt3 + ((size_t)b * 128 + w * 8) * 2048
                               + ln * 32 + 8 * g;

#pragma unroll 2
    for (int ch = 0; ch < 8; ++ch) {
        const unsigned short* kp = kb + ch * 256;    // 32 K-rows x 8 ushorts
        bf16x8 kf0 = (g == 0) ? frag_lo(kp)       : zf.v;
        bf16x8 kf1 = (g == 0) ? frag_lo(kp + 128) : zf.v;
        const unsigned short* vp = vwin + (size_t)ch * 2048;
        bf16x8 vf0 = *(const bf16x8*)(vp);           // c rows ln
        bf16x8 vf1 = *(const bf16x8*)(vp + 512);     // c rows 16+ln
        bf16x8 vf2 = *(const bf16x8*)(vp + 1024);    // c rows 32+ln
        bf16x8 vf3 = *(const bf16x8*)(vp + 1536);    // c rows 48+ln

        const f32x4 z = {0.f, 0.f, 0.f, 0.f};
#pragma unroll
        for (int i = 0; i < 2; ++i) {
            f32x4 s0 = MFMA16(kf0, qf[i], z);
            f32x4 s1 = MFMA16(kf1, qf[i], z);
            F8 pa;
#pragma unroll
            for (int r = 0; r < 4; ++r) {
                pa.h[r]     = (__bf16)EXP2(s0[r]);
                pa.h[r + 4] = (__bf16)EXP2(s1[r]);
            }
            o[i][0] = MFMA16(pa.v, vf0, o[i][0]);
            o[i][1] = MFMA16(pa.v, vf1, o[i][1]);
            o[i][2] = MFMA16(pa.v, vf2, o[i][2]);
            o[i][3] = MFMA16(pa.v, vf3, o[i][3]);
            ol[i]   = MFMA16(pa.v, ones, ol[i]);
        }
    }

    // stash partials: q-row = 16i + 4g + r, c-col = ln + 16j
#pragma unroll
    for (int i = 0; i < 2; ++i) {
#pragma unroll
        for (int r = 0; r < 4; ++r) {
#pragma unroll
            for (int j = 0; j < 4; ++j)
                ldsO[w][16 * i + 4 * g + r][16 * j + ln] = f2bf(o[i][j][r]);
        }
    }
    if (ln == 0) {
#pragma unroll
        for (int i = 0; i < 2; ++i)
#pragma unroll
            for (int r = 0; r < 4; ++r)
                ldsL[w][16 * i + 4 * g + r] = ol[i][r];
    }
    __syncthreads();

    // merge 16 m-slice partials; fused epilogue out = gamma*(O/L) + x
    const int q  = tid & 31;               // query row 0..31
    const int cc = tid >> 5;               // 0..31
    float L = 0.f;
#pragma unroll
    for (int wv = 0; wv < 16; ++wv) L += ldsL[wv][q];
    const float inv = 1.0f / L;
    const float gm  = gamma[0];
#pragma unroll
    for (int j = 0; j < 2; ++j) {
        const int c = cc + 32 * j;         // 0..63
        float Ov = 0.f;
#pragma unroll
        for (int wv = 0; wv < 16; ++wv) Ov += bf2f(ldsO[wv][q][c]);
        const size_t idx = (size_t)(b * 64 + c) * HW + nb + q;
        out[idx] = fmaf(gm, Ov * inv, x[idx]);
    }
}

extern "C" void kernel_launch(void* const* d_in, const int* in_sizes, int n_in,
                              void* d_out, int out_size, void* d_ws, size_t ws_size,
                              hipStream_t stream) {
    const float* x  = (const float*)d_in[0];
    const float* Wq = (const float*)d_in[1];
    const float* bq = (const float*)d_in[2];
    const float* Wk = (const float*)d_in[3];
    const float* bk = (const float*)d_in[4];
    const float* Wv = (const float*)d_in[5];
    const float* bv = (const float*)d_in[6];
    const float* gm = (const float*)d_in[7];

    // ws layout: qpack 256KB | kpack 256KB | vt3 2MB  (total 2.5MB)
    unsigned short* qpack = (unsigned short*)d_ws;
    unsigned short* kpack = qpack + 4 * HW * 8;
    unsigned short* vt3   = kpack + 4 * HW * 8;
    float* out = (float*)d_out;

    proj_kernel<<<1024, 256, 0, stream>>>(x, Wq, bq, Wk, bk, Wv, bv,
                                          qpack, kpack, vt3);
    attn_kernel<<<512, 1024, 0, stream>>>(qpack, kpack, vt3, x, gm, out);
}

// Round 17
// 31.822 us; speedup vs baseline: 1.1472x; 1.1472x over previous
//
#include <hip/hip_runtime.h>

#define HW 4096

typedef float f32x4 __attribute__((ext_vector_type(4)));
typedef __bf16 bf16x8 __attribute__((ext_vector_type(8)));

union F8 { bf16x8 v; unsigned long long q[2]; unsigned short u[8]; __bf16 h[8]; };

__device__ inline unsigned short f2bf(float f) {
    unsigned int u = __builtin_bit_cast(unsigned int, f);
    u += 0x7fffu + ((u >> 16) & 1u);   // RNE
    return (unsigned short)(u >> 16);
}
__device__ inline float bf2f(unsigned short h) {
    unsigned int u = ((unsigned int)h) << 16;
    return __builtin_bit_cast(float, u);
}
__device__ inline bf16x8 frag_lo(const unsigned short* p) {
    F8 f; f.q[0] = *(const unsigned long long*)p; f.q[1] = 0ull; return f.v;
}

#define MFMA16(a,b,c) __builtin_amdgcn_mfma_f32_16x16x32_bf16(a, b, c, 0, 0, 0)
#define EXP2(x) __builtin_amdgcn_exp2f(x)

// ---------------------------------------------------------------------------
// Kernel 1: projections — unchanged (r12 form).
// ---------------------------------------------------------------------------
__global__ __launch_bounds__(256, 4) void proj_kernel(
    const float* __restrict__ x,
    const float* __restrict__ Wq, const float* __restrict__ bq,
    const float* __restrict__ Wk, const float* __restrict__ bk,
    const float* __restrict__ Wv, const float* __restrict__ bv,
    unsigned short* __restrict__ qpack, unsigned short* __restrict__ kpack,
    unsigned short* __restrict__ vt3)
{
    const float A2 = 0.51006977f;      // log2(e)/sqrt(8), folded into q
    __shared__ float ldsW[80][64];
    __shared__ float ldsB[80];

    const int blk   = blockIdx.x;
    const int b     = blk >> 8;
    const int rest  = blk & 255;
    const int ntile = rest >> 2;
    const int rg    = rest & 3;
    const int tid   = threadIdx.x;
    const int w     = tid >> 6;
    const int lane  = tid & 63;
    const int n     = ntile * 64 + lane;

#pragma unroll
    for (int kk = 0; kk < 5; ++kk) {
        const int idx = tid + kk * 256;
        const int r   = idx >> 4;
        const int c   = (idx & 15) << 2;
        f32x4 val;
        if (r < 8) { val = *(const f32x4*)(Wq + r * 64 + c); val *= A2; }
        else if (r < 16) val = *(const f32x4*)(Wk + (r - 8) * 64 + c);
        else             val = *(const f32x4*)(Wv + (r - 16) * 64 + c);
        *(f32x4*)(&ldsW[r][c]) = val;
    }
    if (tid < 80) {
        float bb = (tid < 8) ? bq[tid] * A2
                 : (tid < 16) ? bk[tid - 8] : bv[tid - 16];
        ldsB[tid] = bb;
    }
    __syncthreads();

    const float* xb = x + (size_t)b * 64 * HW + n;
    float xv[64];
#pragma unroll
    for (int c = 0; c < 64; ++c) xv[c] = xb[c * HW];

    auto rowdot = [&](int row) -> float {
        const float* wr = &ldsW[row][0];
        float a0 = 0.f, a1 = 0.f, a2 = 0.f, a3 = 0.f;
#pragma unroll
        for (int c4 = 0; c4 < 16; ++c4) {
            f32x4 wv = *(const f32x4*)(wr + c4 * 4);
            a0 = fmaf(wv[0], xv[c4*4+0], a0);
            a1 = fmaf(wv[1], xv[c4*4+1], a1);
            a2 = fmaf(wv[2], xv[c4*4+2], a2);
            a3 = fmaf(wv[3], xv[c4*4+3], a3);
        }
        return (a0 + a1) + (a2 + a3) + ldsB[row];
    };

    const int vslot = (((n >> 2) & 3) << 3) + (n & 3) + (((n >> 4) & 1) << 2);
    unsigned short* vB = vt3 + ((size_t)(b * 128 + (n >> 5)) * 64) * 32 + vslot;

    const int r0 = rg * 20 + w * 5;
#pragma unroll
    for (int rr = 0; rr < 5; ++rr) {
        const int row = r0 + rr;
        float val = rowdot(row);
        if (row < 8) {
            qpack[(size_t)(b * HW + n) * 8 + row] = f2bf(val);
        } else if (row < 16) {
            kpack[(size_t)(b * HW + n) * 8 + (row - 8)] = f2bf(val);
        } else {
            vB[(size_t)(row - 16) * 32] = f2bf(val);
        }
    }
}

// ---------------------------------------------------------------------------
// Kernel 2: attention + skip, v12 = 4 i-chains AND no duplicated softmax.
// Evidence: v7 (4 chains, 2x exp2) A=24.2 measured; v8 (2 chains, 1x exp2)
// no better -> work reduction and ILP loss cancelled. v11 (2x occupancy)
// regressed -> occupancy exonerated; exp2 issue is occupancy-independent.
// v12 trades residency for registers: (512,1) -> VGPR cap 256 (~150 used),
// 8 waves/CU. Wave = 64q x 64c x 512m (16 chunks): exp2+S-MFMA chip work
// halves vs v7, 4 independent S->exp->PV chains for ILP, V reuse doubled.
// Merge: two-phase bf16 slab-RMW (4 slabs, 37KB LDS static).
// Grid 256 = qt(64) x b(4); XCD slot = (b<<1)|(qt&1).
// ---------------------------------------------------------------------------
__global__ __launch_bounds__(512, 1) void attn_kernel(
    const unsigned short* __restrict__ qpack,
    const unsigned short* __restrict__ kpack,
    const unsigned short* __restrict__ vt3,
    const float* __restrict__ x,
    const float* __restrict__ gamma,
    float* __restrict__ out)
{
    const int blk  = blockIdx.x;
    const int slot = blk & 7;              // XCD slot = (b<<1)|(qt&1)
    const int j32  = blk >> 3;             // 0..31
    const int b    = slot >> 1;
    const int qt   = (j32 << 1) | (slot & 1);  // 0..63
    const int nb   = qt * 64;
    const int tid  = threadIdx.x;
    const int w    = tid >> 6;             // 0..7 = m-slice
    const int lane = tid & 63;
    const int g    = lane >> 4;
    const int ln   = lane & 15;

    __shared__ unsigned short ldsO[4][64][66];   // bf16 partial slabs
    __shared__ float ldsL[8][64];

    F8 zf; zf.q[0] = 0ull; zf.q[1] = 0ull;       // zero fragment (g>=1 pads)

    // Q B-frags for 4 query subtiles: only g=0 lanes carry data
    bf16x8 qf[4];
#pragma unroll
    for (int i = 0; i < 4; ++i)
        qf[i] = (g == 0)
              ? frag_lo(qpack + (size_t)(b * HW + nb + 16 * i + ln) * 8)
              : zf.v;

    F8 onesu;
#pragma unroll
    for (int e = 0; e < 8; ++e) onesu.u[e] = 0x3F80;   // bf16 1.0
    const bf16x8 ones = onesu.v;

    f32x4 o[4][4], ol[4];
#pragma unroll
    for (int i = 0; i < 4; ++i) {
#pragma unroll
        for (int j = 0; j < 4; ++j) o[i][j] = (f32x4){0,0,0,0};
        ol[i] = (f32x4){0,0,0,0};
    }

    const int mq = w * 512;                // this wave's m-slice
    const unsigned short* kb = kpack + (size_t)(b * HW + mq + ln) * 8;
    const unsigned short* vwin = vt3 + ((size_t)b * 128 + w * 16) * 2048
                               + ln * 32 + 8 * g;

#pragma unroll 2
    for (int ch = 0; ch < 16; ++ch) {
        const unsigned short* kp = kb + ch * 256;    // 32 K-rows x 8 ushorts
        bf16x8 kf0 = (g == 0) ? frag_lo(kp)       : zf.v;
        bf16x8 kf1 = (g == 0) ? frag_lo(kp + 128) : zf.v;
        const unsigned short* vp = vwin + (size_t)ch * 2048;
        bf16x8 vf0 = *(const bf16x8*)(vp);           // c rows ln
        bf16x8 vf1 = *(const bf16x8*)(vp + 512);     // c rows 16+ln
        bf16x8 vf2 = *(const bf16x8*)(vp + 1024);    // c rows 32+ln
        bf16x8 vf3 = *(const bf16x8*)(vp + 1536);    // c rows 48+ln

        const f32x4 z = {0.f, 0.f, 0.f, 0.f};
#pragma unroll
        for (int i = 0; i < 4; ++i) {
            f32x4 s0 = MFMA16(kf0, qf[i], z);
            f32x4 s1 = MFMA16(kf1, qf[i], z);
            F8 pa;
#pragma unroll
            for (int r = 0; r < 4; ++r) {
                pa.h[r]     = (__bf16)EXP2(s0[r]);
                pa.h[r + 4] = (__bf16)EXP2(s1[r]);
            }
            o[i][0] = MFMA16(pa.v, vf0, o[i][0]);
            o[i][1] = MFMA16(pa.v, vf1, o[i][1]);
            o[i][2] = MFMA16(pa.v, vf2, o[i][2]);
            o[i][3] = MFMA16(pa.v, vf3, o[i][3]);
            ol[i]   = MFMA16(pa.v, ones, ol[i]);
        }
    }

    // ---- two-phase slab merge ----
    // phase 1: waves 0-3 write slabs 0-3; all waves write their L rows
    if (w < 4) {
#pragma unroll
        for (int i = 0; i < 4; ++i)
#pragma unroll
            for (int r = 0; r < 4; ++r)
#pragma unroll
                for (int j = 0; j < 4; ++j)
                    ldsO[w][16 * i + 4 * g + r][16 * j + ln] = f2bf(o[i][j][r]);
    }
    if (ln == 0) {
#pragma unroll
        for (int i = 0; i < 4; ++i)
#pragma unroll
            for (int r = 0; r < 4; ++r)
                ldsL[w][16 * i + 4 * g + r] = ol[i][r];
    }
    __syncthreads();
    // phase 2: waves 4-7 accumulate into slabs 0-3 (disjoint addresses)
    if (w >= 4) {
        const int s = w - 4;
#pragma unroll
        for (int i = 0; i < 4; ++i)
#pragma unroll
            for (int r = 0; r < 4; ++r)
#pragma unroll
                for (int j = 0; j < 4; ++j) {
                    unsigned short* p = &ldsO[s][16 * i + 4 * g + r][16 * j + ln];
                    *p = f2bf(bf2f(*p) + o[i][j][r]);
                }
    }
    __syncthreads();

    // merge 4 slabs + 8 L rows; fused epilogue out = gamma*(O/L) + x
    const int q  = tid & 63;               // query row 0..63
    const int cg = tid >> 6;               // 0..7
    float L = 0.f;
#pragma unroll
    for (int wv = 0; wv < 8; ++wv) L += ldsL[wv][q];
    const float inv = 1.0f / L;
    const float gm  = gamma[0];
#pragma unroll
    for (int jj = 0; jj < 8; ++jj) {
        const int c = cg + 8 * jj;         // 0..63
        float Ov = bf2f(ldsO[0][q][c]) + bf2f(ldsO[1][q][c])
                 + bf2f(ldsO[2][q][c]) + bf2f(ldsO[3][q][c]);
        const size_t idx = (size_t)(b * 64 + c) * HW + nb + q;
        out[idx] = fmaf(gm, Ov * inv, x[idx]);
    }
}

extern "C" void kernel_launch(void* const* d_in, const int* in_sizes, int n_in,
                              void* d_out, int out_size, void* d_ws, size_t ws_size,
                              hipStream_t stream) {
    const float* x  = (const float*)d_in[0];
    const float* Wq = (const float*)d_in[1];
    const float* bq = (const float*)d_in[2];
    const float* Wk = (const float*)d_in[3];
    const float* bk = (const float*)d_in[4];
    const float* Wv = (const float*)d_in[5];
    const float* bv = (const float*)d_in[6];
    const float* gm = (const float*)d_in[7];

    // ws layout: qpack 256KB | kpack 256KB | vt3 2MB  (total 2.5MB)
    unsigned short* qpack = (unsigned short*)d_ws;
    unsigned short* kpack = qpack + 4 * HW * 8;
    unsigned short* vt3   = kpack + 4 * HW * 8;
    float* out = (float*)d_out;

    proj_kernel<<<1024, 256, 0, stream>>>(x, Wq, bq, Wk, bk, Wv, bv,
                                          qpack, kpack, vt3);
    attn_kernel<<<256, 512, 0, stream>>>(qpack, kpack, vt3, x, gm, out);
}